// Round 1
// baseline (9301.638 us; speedup 1.0000x reference)
//
#include <hip/hip_runtime.h>
#include <hip/hip_cooperative_groups.h>

namespace cg = cooperative_groups;

typedef unsigned short u16;
typedef __attribute__((ext_vector_type(8))) short bf16x8;
typedef __attribute__((ext_vector_type(4))) float f32x4;

#define MFMA_BF16(a, b, c) __builtin_amdgcn_mfma_f32_16x16x32_bf16((a), (b), (c), 0, 0, 0)

#define GLD16(gp, lp)                                                        \
  __builtin_amdgcn_global_load_lds(                                          \
      (const __attribute__((address_space(1))) void*)(gp),                   \
      (__attribute__((address_space(3))) void*)(lp), 16, 0, 0)

__device__ __forceinline__ u16 f2bf(float f) {
  union { float f; unsigned u; } v;
  v.f = f;
  unsigned r = v.u + 0x7FFFu + ((v.u >> 16) & 1u);
  return (u16)(r >> 16);
}
__device__ __forceinline__ float sigf(float x) { return 1.0f / (1.0f + __expf(-x)); }
__device__ __forceinline__ float tanh_(float x) { return 1.0f - 2.0f / (__expf(2.0f * x) + 1.0f); }

// ---- x (fp32) -> bf16, vectorized ----
__global__ void k_cvt_x(const float* __restrict__ src, u16* __restrict__ dst, int n4) {
  int i = blockIdx.x * blockDim.x + threadIdx.x;
  int st = gridDim.x * blockDim.x;
  for (; i < n4; i += st) {
    float4 v = reinterpret_cast<const float4*>(src)[i];
    ushort4 o;
    o.x = f2bf(v.x); o.y = f2bf(v.y); o.z = f2bf(v.z); o.w = f2bf(v.w);
    reinterpret_cast<ushort4*>(dst)[i] = o;
  }
}

// ---- transpose (R x C fp32) -> (C x R bf16), 64x64 LDS tiles ----
__global__ void k_transpose_cvt(const float* __restrict__ src, u16* __restrict__ dst,
                                int R, int C) {
  __shared__ float tile[64][65];
  int c0 = blockIdx.x * 64, r0 = blockIdx.y * 64;
  int tx = threadIdx.x & 63, ty = threadIdx.x >> 6;
#pragma unroll
  for (int q = 0; q < 16; ++q) {
    int r = ty + q * 4;
    tile[r][tx] = src[(size_t)(r0 + r) * C + c0 + tx];
  }
  __syncthreads();
#pragma unroll
  for (int q = 0; q < 16; ++q) {
    int r = ty + q * 4;
    dst[(size_t)(c0 + r) * R + r0 + tx] = f2bf(tile[tx][r]);
  }
}

// ---- initial state: h0 -> hbuf[0] (bf16), c0 -> cws (fp32) ----
__global__ void k_init(const float* __restrict__ h0, const float* __restrict__ c0,
                       u16* __restrict__ hbuf, float* __restrict__ cws) {
  int i = blockIdx.x * 256 + threadIdx.x;  // 65536 total
  hbuf[i] = f2bf(h0[i]);
  cws[i] = c0[i];
}

// ---- xz = x@Wi + b for a time-chunk; 128x128 tile, BK=32, global_load_lds ----
__global__ __launch_bounds__(256) void k_gemm_xz(
    const u16* __restrict__ xb,   // [64][256][1024] bf16
    const u16* __restrict__ wiT,  // [4096][1024] bf16 (Wi transposed)
    const float* __restrict__ bias,
    float* __restrict__ xz,       // [64*Tc][4096] fp32
    int t0, int lgTc) {
  __shared__ u16 Al[128 * 32];
  __shared__ u16 Bl[128 * 32];
  const int tid = threadIdx.x;
  const int w = tid >> 6, l = tid & 63;
  const int lc = l & 15, lg = l >> 4;
  const int ntm = 1 << (lgTc - 1);            // (64*Tc)/128
  const int tm = blockIdx.x & (ntm - 1);
  const int tn = blockIdx.x >> (lgTc - 1);
  const int m0 = tm << 7, n0 = tn << 7;
  const int mask = (1 << lgTc) - 1;

  const int rowl = w * 32 + (l >> 2);
  const int koff = (l & 3) * 8;
  const int mA0 = m0 + rowl, mA1 = mA0 + 16;
  const size_t xr0 = ((size_t)(mA0 >> lgTc) * 256 + t0 + (mA0 & mask)) * 1024 + koff;
  const size_t xr1 = ((size_t)(mA1 >> lgTc) * 256 + t0 + (mA1 & mask)) * 1024 + koff;
  const size_t br0 = (size_t)(n0 + rowl) * 1024 + koff;
  const size_t br1 = br0 + 16 * 1024;

  u16* a_dst0 = &Al[w * 1024];
  u16* a_dst1 = &Al[w * 1024 + 512];
  u16* b_dst0 = &Bl[w * 1024];
  u16* b_dst1 = &Bl[w * 1024 + 512];

  f32x4 acc[4][4] = {};

  for (int k0 = 0; k0 < 1024; k0 += 32) {
    GLD16(xb + xr0 + k0, a_dst0);
    GLD16(xb + xr1 + k0, a_dst1);
    GLD16(wiT + br0 + k0, b_dst0);
    GLD16(wiT + br1 + k0, b_dst1);
    __syncthreads();
    bf16x8 af[4], bfr[4];
#pragma unroll
    for (int mi = 0; mi < 4; ++mi)
      af[mi] = *(const bf16x8*)&Al[((w & 1) * 64 + mi * 16 + lc) * 32 + lg * 8];
#pragma unroll
    for (int ni = 0; ni < 4; ++ni)
      bfr[ni] = *(const bf16x8*)&Bl[((w >> 1) * 64 + ni * 16 + lc) * 32 + lg * 8];
#pragma unroll
    for (int mi = 0; mi < 4; ++mi)
#pragma unroll
      for (int ni = 0; ni < 4; ++ni)
        acc[mi][ni] = MFMA_BF16(af[mi], bfr[ni], acc[mi][ni]);
    __syncthreads();
  }

  const int mbase = m0 + (w & 1) * 64 + lg * 4;
  const int nbase = n0 + (w >> 1) * 64 + lc;
#pragma unroll
  for (int ni = 0; ni < 4; ++ni) {
    const int n = nbase + ni * 16;
    const float bv = bias[n];
#pragma unroll
    for (int mi = 0; mi < 4; ++mi) {
#pragma unroll
      for (int r = 0; r < 4; ++r) {
        const int m = mbase + mi * 16 + r;
        xz[(size_t)m * 4096 + n] = acc[mi][ni][r] + bv;
      }
    }
  }
}

// ---- cooperative recurrence: 256 wgs x 256 thr; wg owns 4 h-cols (16 gate cols);
//      Wh slice in VGPRs; h broadcast via bf16 double buffer; c in registers ----
__global__ void __launch_bounds__(256, 1) k_recur(
    const u16* __restrict__ whT,   // [4096][1024] bf16 (Wh transposed)
    const float* __restrict__ xz,  // [64*Tc][4096] fp32
    u16* __restrict__ hbuf,        // [2][64*1024] bf16
    float* __restrict__ cws,       // [64*1024] fp32
    float* __restrict__ out,       // [64][256][1024] fp32
    int t0, int Tc) {
  cg::grid_group grid = cg::this_grid();
  __shared__ float zl[64][17];
  const int tid = threadIdx.x;
  const int wg = blockIdx.x;
  const int w = tid >> 6, l = tid & 63;
  const int lc = l & 15, lg = l >> 4;

  // B-fragments of the owned Wh slice, kept in registers for the whole launch.
  // column c=lc -> n = (c>>2)*1024 + wg*4 + (c&3)  (gate-major: i,f,g,o)
  const size_t wrow = ((size_t)(lc >> 2) * 1024 + wg * 4 + (lc & 3)) * 1024;
  bf16x8 bw[32];
#pragma unroll
  for (int kb = 0; kb < 32; ++kb)
    bw[kb] = *(const bf16x8*)(whT + wrow + kb * 32 + lg * 8);

  const int cb = tid >> 2, cj = tid & 3;  // (batch, owned-col) for gate phase
  const int ccol = wg * 4 + cj;
  float creg = cws[cb * 1024 + ccol];

  const unsigned abase = (unsigned)((16 * w + lc) * 1024 + lg * 8);

  for (int tt = 0; tt < Tc; ++tt) {
    const int t = t0 + tt;
    const u16* hp = hbuf + (size_t)(t & 1) * 65536 + abase;
    f32x4 ac0 = {0.f, 0.f, 0.f, 0.f}, ac1 = {0.f, 0.f, 0.f, 0.f};
    bf16x8 ar[8];
#pragma unroll
    for (int q = 0; q < 8; ++q) ar[q] = *(const bf16x8*)(hp + q * 32);
#pragma unroll
    for (int kb = 0; kb < 32; ++kb) {
      bf16x8 a = ar[kb & 7];
      if (kb < 24) ar[kb & 7] = *(const bf16x8*)(hp + (kb + 8) * 32);
      if (kb & 1) ac1 = MFMA_BF16(a, bw[kb], ac1);
      else        ac0 = MFMA_BF16(a, bw[kb], ac0);
    }
#pragma unroll
    for (int r = 0; r < 4; ++r)
      zl[16 * w + lg * 4 + r][lc] = ac0[r] + ac1[r];
    __syncthreads();

    // gate phase: one thread per (batch, owned col)
    const float* xzp = xz + (size_t)(cb * Tc + tt) * 4096 + ccol;
    const float zi = zl[cb][cj]      + xzp[0];
    const float zf = zl[cb][4 + cj]  + xzp[1024];
    const float zg = zl[cb][8 + cj]  + xzp[2048];
    const float zo = zl[cb][12 + cj] + xzp[3072];
    const float cn = sigf(zf) * creg + sigf(zi) * tanh_(zg);
    const float hn = sigf(zo) * tanh_(cn);
    creg = cn;
    out[((size_t)cb * 256 + t) * 1024 + ccol] = hn;
    hbuf[(size_t)((t + 1) & 1) * 65536 + cb * 1024 + ccol] = f2bf(hn);
    grid.sync();
  }
  cws[cb * 1024 + ccol] = creg;
}

extern "C" void kernel_launch(void* const* d_in, const int* in_sizes, int n_in,
                              void* d_out, int out_size, void* d_ws, size_t ws_size,
                              hipStream_t stream) {
  const float* x    = (const float*)d_in[0];
  const float* h0   = (const float*)d_in[1];
  const float* c0   = (const float*)d_in[2];
  const float* Wi   = (const float*)d_in[3];
  const float* Wh   = (const float*)d_in[4];
  const float* bias = (const float*)d_in[5];
  float* out = (float*)d_out;

  char* ws = (char*)d_ws;
  u16*   xb   = (u16*)(ws);                   // 33,554,432 B : x in bf16
  u16*   wiT  = (u16*)(ws + 33554432);        //  8,388,608 B : Wi^T bf16
  u16*   whT  = (u16*)(ws + 41943040);        //  8,388,608 B : Wh^T bf16
  u16*   hbuf = (u16*)(ws + 50331648);        //    262,144 B : h double-buffer bf16
  float* cws  = (float*)(ws + 50593792);      //    262,144 B : c state fp32
  float* xz   = (float*)(ws + 50855936);      // Tc*1,048,576 B : xz chunk fp32

  int lgTc = 0;
  for (int lg = 8; lg >= 1; --lg) {
    if (50855936ull + (1ull << lg) * 1048576ull <= ws_size) { lgTc = lg; break; }
  }
  if (lgTc == 0) return;  // workspace too small — fail visibly
  const int Tc = 1 << lgTc;

  k_cvt_x<<<2048, 256, 0, stream>>>(x, xb, (64 * 256 * 1024) / 4);
  dim3 tg(4096 / 64, 1024 / 64);
  k_transpose_cvt<<<tg, 256, 0, stream>>>(Wi, wiT, 1024, 4096);
  k_transpose_cvt<<<tg, 256, 0, stream>>>(Wh, whT, 1024, 4096);
  k_init<<<256, 256, 0, stream>>>(h0, c0, hbuf, cws);

  for (int t0 = 0; t0 < 256; t0 += Tc) {
    k_gemm_xz<<<dim3((64 * Tc / 128) * 32), 256, 0, stream>>>(xb, wiT, bias, xz, t0, lgTc);
    const u16* whT_ = whT;
    const float* xz_ = xz;
    u16* hbuf_ = hbuf;
    float* cws_ = cws;
    float* out_ = out;
    int t0_ = t0, Tc_ = Tc;
    void* args[7] = {(void*)&whT_, (void*)&xz_, (void*)&hbuf_, (void*)&cws_,
                     (void*)&out_, (void*)&t0_, (void*)&Tc_};
    hipLaunchCooperativeKernel((void*)k_recur, dim3(256), dim3(256), args, 0, stream);
  }
}

// Round 2
// 8197.447 us; speedup vs baseline: 1.1347x; 1.1347x over previous
//
#include <hip/hip_runtime.h>

typedef unsigned short u16;
typedef __attribute__((ext_vector_type(8))) short bf16x8;
typedef __attribute__((ext_vector_type(4))) float f32x4;

#define MFMA_BF16(a, b, c) __builtin_amdgcn_mfma_f32_16x16x32_bf16((a), (b), (c), 0, 0, 0)

#define GLD16(gp, lp)                                                        \
  __builtin_amdgcn_global_load_lds(                                          \
      (const __attribute__((address_space(1))) void*)(gp),                   \
      (__attribute__((address_space(3))) void*)(lp), 16, 0, 0)

__device__ __forceinline__ u16 f2bf(float f) {
  union { float f; unsigned u; } v;
  v.f = f;
  unsigned r = v.u + 0x7FFFu + ((v.u >> 16) & 1u);
  return (u16)(r >> 16);
}
__device__ __forceinline__ float sigf(float x) { return 1.0f / (1.0f + __expf(-x)); }
__device__ __forceinline__ float tanh_(float x) { return 1.0f - 2.0f / (__expf(2.0f * x) + 1.0f); }
// XOR-swizzle: spreads both row-major reads (rows in bits 11+) and chunked
// writes (chunks in bits 7+) across the 8 16B-slots of the 32 LDS banks.
__device__ __forceinline__ unsigned swz(unsigned b) {
  return b ^ ((((b >> 11) ^ (b >> 7)) & 7u) << 4);
}

// ---- x (fp32) -> bf16, vectorized ----
__global__ void k_cvt_x(const float* __restrict__ src, u16* __restrict__ dst, int n4) {
  int i = blockIdx.x * blockDim.x + threadIdx.x;
  int st = gridDim.x * blockDim.x;
  for (; i < n4; i += st) {
    float4 v = reinterpret_cast<const float4*>(src)[i];
    ushort4 o;
    o.x = f2bf(v.x); o.y = f2bf(v.y); o.z = f2bf(v.z); o.w = f2bf(v.w);
    reinterpret_cast<ushort4*>(dst)[i] = o;
  }
}

// ---- transpose (R x C fp32) -> (C x R bf16), 64x64 LDS tiles ----
__global__ void k_transpose_cvt(const float* __restrict__ src, u16* __restrict__ dst,
                                int R, int C) {
  __shared__ float tile[64][65];
  int c0 = blockIdx.x * 64, r0 = blockIdx.y * 64;
  int tx = threadIdx.x & 63, ty = threadIdx.x >> 6;
#pragma unroll
  for (int q = 0; q < 16; ++q) {
    int r = ty + q * 4;
    tile[r][tx] = src[(size_t)(r0 + r) * C + c0 + tx];
  }
  __syncthreads();
#pragma unroll
  for (int q = 0; q < 16; ++q) {
    int r = ty + q * 4;
    dst[(size_t)(c0 + r) * R + r0 + tx] = f2bf(tile[tx][r]);
  }
}

// ---- initial state: h0 -> hbuf[0] (bf16), c0 -> cws (fp32), zero barrier flags ----
__global__ void k_init(const float* __restrict__ h0, const float* __restrict__ c0,
                       u16* __restrict__ hbuf, float* __restrict__ cws,
                       unsigned* __restrict__ flags) {
  int i = blockIdx.x * 256 + threadIdx.x;  // 65536 total
  hbuf[i] = f2bf(h0[i]);
  cws[i] = c0[i];
  if (i < 4096) flags[i] = 0u;
}

// ---- xz = x@Wi + b for a time-chunk; 128x128 tile, BK=32, global_load_lds ----
__global__ __launch_bounds__(256) void k_gemm_xz(
    const u16* __restrict__ xb,   // [64][256][1024] bf16
    const u16* __restrict__ wiT,  // [4096][1024] bf16 (Wi transposed)
    const float* __restrict__ bias,
    float* __restrict__ xz,       // [64*Tc][4096] fp32
    int t0, int lgTc) {
  __shared__ u16 Al[128 * 32];
  __shared__ u16 Bl[128 * 32];
  const int tid = threadIdx.x;
  const int w = tid >> 6, l = tid & 63;
  const int lc = l & 15, lg = l >> 4;
  const int ntm = 1 << (lgTc - 1);            // (64*Tc)/128
  const int tm = blockIdx.x & (ntm - 1);
  const int tn = blockIdx.x >> (lgTc - 1);
  const int m0 = tm << 7, n0 = tn << 7;
  const int mask = (1 << lgTc) - 1;

  const int rowl = w * 32 + (l >> 2);
  const int koff = (l & 3) * 8;
  const int mA0 = m0 + rowl, mA1 = mA0 + 16;
  const size_t xr0 = ((size_t)(mA0 >> lgTc) * 256 + t0 + (mA0 & mask)) * 1024 + koff;
  const size_t xr1 = ((size_t)(mA1 >> lgTc) * 256 + t0 + (mA1 & mask)) * 1024 + koff;
  const size_t br0 = (size_t)(n0 + rowl) * 1024 + koff;
  const size_t br1 = br0 + 16 * 1024;

  u16* a_dst0 = &Al[w * 1024];
  u16* a_dst1 = &Al[w * 1024 + 512];
  u16* b_dst0 = &Bl[w * 1024];
  u16* b_dst1 = &Bl[w * 1024 + 512];

  f32x4 acc[4][4] = {};

  for (int k0 = 0; k0 < 1024; k0 += 32) {
    GLD16(xb + xr0 + k0, a_dst0);
    GLD16(xb + xr1 + k0, a_dst1);
    GLD16(wiT + br0 + k0, b_dst0);
    GLD16(wiT + br1 + k0, b_dst1);
    __syncthreads();
    bf16x8 af[4], bfr[4];
#pragma unroll
    for (int mi = 0; mi < 4; ++mi)
      af[mi] = *(const bf16x8*)&Al[((w & 1) * 64 + mi * 16 + lc) * 32 + lg * 8];
#pragma unroll
    for (int ni = 0; ni < 4; ++ni)
      bfr[ni] = *(const bf16x8*)&Bl[((w >> 1) * 64 + ni * 16 + lc) * 32 + lg * 8];
#pragma unroll
    for (int mi = 0; mi < 4; ++mi)
#pragma unroll
      for (int ni = 0; ni < 4; ++ni)
        acc[mi][ni] = MFMA_BF16(af[mi], bfr[ni], acc[mi][ni]);
    __syncthreads();
  }

  const int mbase = m0 + (w & 1) * 64 + lg * 4;
  const int nbase = n0 + (w >> 1) * 64 + lc;
#pragma unroll
  for (int ni = 0; ni < 4; ++ni) {
    const int n = nbase + ni * 16;
    const float bv = bias[n];
#pragma unroll
    for (int mi = 0; mi < 4; ++mi) {
#pragma unroll
      for (int r = 0; r < 4; ++r) {
        const int m = mbase + mi * 16 + r;
        xz[(size_t)m * 4096 + n] = acc[mi][ni][r] + bv;
      }
    }
  }
}

// ---- recurrence: 4 independent groups x 64 wgs; group g owns batches
//      [16g,16g+16); wg owns 16 h-cols x 4 gates; Wh slice in LDS (swizzled)
//      + hoisted to VGPR B-frags; custom per-group flag barrier per step ----
__global__ void __launch_bounds__(256, 1) k_recur(
    const u16* __restrict__ whT,   // [4096][1024] bf16 (Wh transposed)
    const float* __restrict__ xz,  // [64*Tc][4096] fp32
    u16* __restrict__ hbuf,        // [2][64*1024] bf16
    float* __restrict__ cws,       // [64*1024] fp32
    float* __restrict__ out,       // [64][256][1024] fp32
    unsigned* __restrict__ flags,  // [256] x 16 u32 (cacheline-padded)
    int t0, int Tc) {
  __shared__ u16 Wl[64 * 1024];    // 128 KiB: 64 gate-col rows x 1024 k (swizzled)
  __shared__ float zl[4][16][17];  // [gate][batch][hcol]
  const int tid = threadIdx.x;
  const int wgid = blockIdx.x;
  const int g = wgid >> 6, gi = wgid & 63;
  const int bg = g * 16, hc0 = gi * 16;
  const int w = tid >> 6, l = tid & 63;
  const int lc = l & 15, lg = l >> 4;
  const int mb = tid >> 4, j = tid & 15;

  // ---- stage Wh slice -> LDS (swizzled), once ----
  for (int rb = 0; rb < 4; ++rb) {
    const int r = rb * 16 + (tid & 15);       // LDS row = q*16 + jj
    const int chunk = tid >> 4;               // 64-elem column chunk
    const int q = r >> 4, jj = r & 15;
    const u16* src = whT + ((size_t)(q * 1024 + hc0 + jj)) * 1024 + chunk * 64;
#pragma unroll
    for (int v = 0; v < 8; ++v) {
      bf16x8 d = *(const bf16x8*)(src + v * 8);
      *(bf16x8*)((char*)Wl + swz((unsigned)(r * 2048 + chunk * 128 + v * 16))) = d;
    }
  }
  __syncthreads();

  // ---- hoist B-fragments to registers (static indices only) ----
  const unsigned bbase = (unsigned)((w * 16 + lc) * 2048 + lg * 16);
  bf16x8 bw[32];
#pragma unroll
  for (int kb = 0; kb < 32; ++kb)
    bw[kb] = *(const bf16x8*)((char*)Wl + swz(bbase + kb * 64));

  float creg = cws[(size_t)(bg + mb) * 1024 + hc0 + j];
  unsigned* myflag = flags + (size_t)wgid * 16;
  unsigned* gflag = flags + (size_t)(g * 64 + (tid & 63)) * 16;

  for (int tt = 0; tt < Tc; ++tt) {
    const int t = t0 + tt;
    // prefetch xz for this step (independent of h)
    const float* xp = xz + ((size_t)(bg + mb) * Tc + tt) * 4096 + hc0 + j;
    const float x0 = xp[0], x1 = xp[1024], x2 = xp[2048], x3 = xp[3072];

    // A-frags straight from global (L2/L3); rows = group's 16 batches
    const u16* hp = hbuf + (size_t)(t & 1) * 65536 + (size_t)(bg + lc) * 1024 + lg * 8;
    f32x4 ac0 = {0.f, 0.f, 0.f, 0.f}, ac1 = {0.f, 0.f, 0.f, 0.f};
#pragma unroll
    for (int kb = 0; kb < 32; kb += 2) {
      bf16x8 a0 = *(const bf16x8*)(hp + (size_t)kb * 32);
      bf16x8 a1 = *(const bf16x8*)(hp + (size_t)kb * 32 + 32);
      ac0 = MFMA_BF16(a0, bw[kb], ac0);
      ac1 = MFMA_BF16(a1, bw[kb + 1], ac1);
    }
#pragma unroll
    for (int r = 0; r < 4; ++r) zl[w][lg * 4 + r][lc] = ac0[r] + ac1[r];
    __syncthreads();

    // gate phase: thread (mb, j) owns (batch bg+mb, h-col hc0+j)
    const float zi = zl[0][mb][j] + x0;
    const float zf = zl[1][mb][j] + x1;
    const float zg = zl[2][mb][j] + x2;
    const float zo = zl[3][mb][j] + x3;
    const float cn = sigf(zf) * creg + sigf(zi) * tanh_(zg);
    const float hn = sigf(zo) * tanh_(cn);
    creg = cn;
    out[((size_t)(bg + mb) * 256 + t) * 1024 + hc0 + j] = hn;
    hbuf[(size_t)((t + 1) & 1) * 65536 + (size_t)(bg + mb) * 1024 + hc0 + j] = f2bf(hn);

    // ---- per-group barrier: release fence, flag store, wave-0 spin, acquire ----
    __threadfence();
    __syncthreads();
    if (tid < 64) {
      if (tid == 0)
        __hip_atomic_store(myflag, (unsigned)(t + 1), __ATOMIC_RELAXED,
                           __HIP_MEMORY_SCOPE_AGENT);
      unsigned v;
      do {
        v = __hip_atomic_load(gflag, __ATOMIC_RELAXED, __HIP_MEMORY_SCOPE_AGENT);
      } while (v < (unsigned)(t + 1));
      __threadfence();
    }
    __syncthreads();
  }
  cws[(size_t)(bg + mb) * 1024 + hc0 + j] = creg;
}

extern "C" void kernel_launch(void* const* d_in, const int* in_sizes, int n_in,
                              void* d_out, int out_size, void* d_ws, size_t ws_size,
                              hipStream_t stream) {
  const float* x    = (const float*)d_in[0];
  const float* h0   = (const float*)d_in[1];
  const float* c0   = (const float*)d_in[2];
  const float* Wi   = (const float*)d_in[3];
  const float* Wh   = (const float*)d_in[4];
  const float* bias = (const float*)d_in[5];
  float* out = (float*)d_out;

  char* ws = (char*)d_ws;
  u16*      xb    = (u16*)(ws);                   // 33,554,432 B : x in bf16
  u16*      wiT   = (u16*)(ws + 33554432);        //  8,388,608 B : Wi^T bf16
  u16*      whT   = (u16*)(ws + 41943040);        //  8,388,608 B : Wh^T bf16
  u16*      hbuf  = (u16*)(ws + 50331648);        //    262,144 B : h double-buffer bf16
  float*    cws   = (float*)(ws + 50593792);      //    262,144 B : c state fp32
  unsigned* flags = (unsigned*)(ws + 50855936);   //     16,384 B : barrier flags
  float*    xz    = (float*)(ws + 50872320);      // Tc*1,048,576 B : xz chunk fp32

  int lgTc = 0;
  for (int lg = 8; lg >= 1; --lg) {
    if (50872320ull + (1ull << lg) * 1048576ull <= ws_size) { lgTc = lg; break; }
  }
  if (lgTc == 0) return;  // workspace too small — fail visibly
  const int Tc = 1 << lgTc;

  k_cvt_x<<<2048, 256, 0, stream>>>(x, xb, (64 * 256 * 1024) / 4);
  dim3 tg(4096 / 64, 1024 / 64);
  k_transpose_cvt<<<tg, 256, 0, stream>>>(Wi, wiT, 1024, 4096);
  k_transpose_cvt<<<tg, 256, 0, stream>>>(Wh, whT, 1024, 4096);
  k_init<<<256, 256, 0, stream>>>(h0, c0, hbuf, cws, flags);

  for (int t0 = 0; t0 < 256; t0 += Tc) {
    k_gemm_xz<<<dim3((64 * Tc / 128) * 32), 256, 0, stream>>>(xb, wiT, bias, xz, t0, lgTc);
    const u16* whT_ = whT;
    const float* xz_ = xz;
    u16* hbuf_ = hbuf;
    float* cws_ = cws;
    float* out_ = out;
    unsigned* flags_ = flags;
    int t0_ = t0, Tc_ = Tc;
    void* args[8] = {(void*)&whT_, (void*)&xz_, (void*)&hbuf_, (void*)&cws_,
                     (void*)&out_, (void*)&flags_, (void*)&t0_, (void*)&Tc_};
    hipLaunchCooperativeKernel((void*)k_recur, dim3(256), dim3(256), args, 0, stream);
  }
}

// Round 3
// 2807.022 us; speedup vs baseline: 3.3137x; 2.9203x over previous
//
#include <hip/hip_runtime.h>

typedef unsigned short u16;
typedef unsigned long long u64;
typedef __attribute__((ext_vector_type(8))) short bf16x8;
typedef __attribute__((ext_vector_type(4))) float f32x4;

#define MFMA_BF16(a, b, c) __builtin_amdgcn_mfma_f32_16x16x32_bf16((a), (b), (c), 0, 0, 0)

#define GLD16(gp, lp)                                                        \
  __builtin_amdgcn_global_load_lds(                                          \
      (const __attribute__((address_space(1))) void*)(gp),                   \
      (__attribute__((address_space(3))) void*)(lp), 16, 0, 0)

#define ALOAD64(p)  __hip_atomic_load((p), __ATOMIC_RELAXED, __HIP_MEMORY_SCOPE_AGENT)
#define ALOAD32(p)  __hip_atomic_load((p), __ATOMIC_RELAXED, __HIP_MEMORY_SCOPE_AGENT)
#define ASTORE32(p, v) __hip_atomic_store((p), (v), __ATOMIC_RELAXED, __HIP_MEMORY_SCOPE_AGENT)

__device__ __forceinline__ u16 f2bf(float f) {
  union { float f; unsigned u; } v;
  v.f = f;
  unsigned r = v.u + 0x7FFFu + ((v.u >> 16) & 1u);
  return (u16)(r >> 16);
}
__device__ __forceinline__ float sigf(float x) { return 1.0f / (1.0f + __expf(-x)); }
__device__ __forceinline__ float tanh_(float x) { return 1.0f - 2.0f / (__expf(2.0f * x) + 1.0f); }
// XOR-swizzle: spreads both row-major reads (rows in bits 11+) and chunked
// writes (chunks in bits 7+) across the 8 16B-slots of the 32 LDS banks.
__device__ __forceinline__ unsigned swz(unsigned b) {
  return b ^ ((((b >> 11) ^ (b >> 7)) & 7u) << 4);
}

// ---- x (fp32) -> bf16, vectorized ----
__global__ void k_cvt_x(const float* __restrict__ src, u16* __restrict__ dst, int n4) {
  int i = blockIdx.x * blockDim.x + threadIdx.x;
  int st = gridDim.x * blockDim.x;
  for (; i < n4; i += st) {
    float4 v = reinterpret_cast<const float4*>(src)[i];
    ushort4 o;
    o.x = f2bf(v.x); o.y = f2bf(v.y); o.z = f2bf(v.z); o.w = f2bf(v.w);
    reinterpret_cast<ushort4*>(dst)[i] = o;
  }
}

// ---- transpose (R x C fp32) -> (C x R bf16), 64x64 LDS tiles ----
__global__ void k_transpose_cvt(const float* __restrict__ src, u16* __restrict__ dst,
                                int R, int C) {
  __shared__ float tile[64][65];
  int c0 = blockIdx.x * 64, r0 = blockIdx.y * 64;
  int tx = threadIdx.x & 63, ty = threadIdx.x >> 6;
#pragma unroll
  for (int q = 0; q < 16; ++q) {
    int r = ty + q * 4;
    tile[r][tx] = src[(size_t)(r0 + r) * C + c0 + tx];
  }
  __syncthreads();
#pragma unroll
  for (int q = 0; q < 16; ++q) {
    int r = ty + q * 4;
    dst[(size_t)(c0 + r) * R + r0 + tx] = f2bf(tile[tx][r]);
  }
}

// ---- initial state: h0 -> hbuf[0] (bf16), c0 -> cws (fp32), zero barrier flags ----
__global__ void k_init(const float* __restrict__ h0, const float* __restrict__ c0,
                       u16* __restrict__ hbuf, float* __restrict__ cws,
                       unsigned* __restrict__ flags) {
  int i = blockIdx.x * 256 + threadIdx.x;  // 65536 total
  hbuf[i] = f2bf(h0[i]);
  cws[i] = c0[i];
  if (i < 8192) flags[i] = 0u;
}

// ---- xz = x@Wi + b for a time-chunk; 128x128 tile, BK=32, global_load_lds ----
__global__ __launch_bounds__(256) void k_gemm_xz(
    const u16* __restrict__ xb,   // [64][256][1024] bf16
    const u16* __restrict__ wiT,  // [4096][1024] bf16 (Wi transposed)
    const float* __restrict__ bias,
    float* __restrict__ xz,       // [64*Tc][4096] fp32
    int t0, int lgTc) {
  __shared__ u16 Al[128 * 32];
  __shared__ u16 Bl[128 * 32];
  const int tid = threadIdx.x;
  const int w = tid >> 6, l = tid & 63;
  const int lc = l & 15, lg = l >> 4;
  const int ntm = 1 << (lgTc - 1);            // (64*Tc)/128
  const int tm = blockIdx.x & (ntm - 1);
  const int tn = blockIdx.x >> (lgTc - 1);
  const int m0 = tm << 7, n0 = tn << 7;
  const int mask = (1 << lgTc) - 1;

  const int rowl = w * 32 + (l >> 2);
  const int koff = (l & 3) * 8;
  const int mA0 = m0 + rowl, mA1 = mA0 + 16;
  const size_t xr0 = ((size_t)(mA0 >> lgTc) * 256 + t0 + (mA0 & mask)) * 1024 + koff;
  const size_t xr1 = ((size_t)(mA1 >> lgTc) * 256 + t0 + (mA1 & mask)) * 1024 + koff;
  const size_t br0 = (size_t)(n0 + rowl) * 1024 + koff;
  const size_t br1 = br0 + 16 * 1024;

  u16* a_dst0 = &Al[w * 1024];
  u16* a_dst1 = &Al[w * 1024 + 512];
  u16* b_dst0 = &Bl[w * 1024];
  u16* b_dst1 = &Bl[w * 1024 + 512];

  f32x4 acc[4][4] = {};

  for (int k0 = 0; k0 < 1024; k0 += 32) {
    GLD16(xb + xr0 + k0, a_dst0);
    GLD16(xb + xr1 + k0, a_dst1);
    GLD16(wiT + br0 + k0, b_dst0);
    GLD16(wiT + br1 + k0, b_dst1);
    __syncthreads();
    bf16x8 af[4], bfr[4];
#pragma unroll
    for (int mi = 0; mi < 4; ++mi)
      af[mi] = *(const bf16x8*)&Al[((w & 1) * 64 + mi * 16 + lc) * 32 + lg * 8];
#pragma unroll
    for (int ni = 0; ni < 4; ++ni)
      bfr[ni] = *(const bf16x8*)&Bl[((w >> 1) * 64 + ni * 16 + lc) * 32 + lg * 8];
#pragma unroll
    for (int mi = 0; mi < 4; ++mi)
#pragma unroll
      for (int ni = 0; ni < 4; ++ni)
        acc[mi][ni] = MFMA_BF16(af[mi], bfr[ni], acc[mi][ni]);
    __syncthreads();
  }

  const int mbase = m0 + (w & 1) * 64 + lg * 4;
  const int nbase = n0 + (w >> 1) * 64 + lc;
#pragma unroll
  for (int ni = 0; ni < 4; ++ni) {
    const int n = nbase + ni * 16;
    const float bv = bias[n];
#pragma unroll
    for (int mi = 0; mi < 4; ++mi) {
#pragma unroll
      for (int r = 0; r < 4; ++r) {
        const int m = mbase + mi * 16 + r;
        xz[(size_t)m * 4096 + n] = acc[mi][ni][r] + bv;
      }
    }
  }
}

// ---- recurrence: 4 independent groups x 64 wgs; group g owns batches
//      [16g,16g+16); wg owns 16 h-cols x 4 gates; Wh slice in LDS (swizzled).
//      ALL h-state traffic is relaxed agent-scope (sc1, LLC-coherent) so NO
//      fences / L2 cache-maintenance ops are needed anywhere in the loop. ----
__global__ void __launch_bounds__(256, 1) k_recur(
    const u16* __restrict__ whT,   // [4096][1024] bf16 (Wh transposed)
    const float* __restrict__ xz,  // [64*Tc][4096] fp32
    u16* __restrict__ hbuf,        // [2][64*1024] bf16
    float* __restrict__ cws,       // [64*1024] fp32
    float* __restrict__ out,       // [64][256][1024] fp32
    unsigned* __restrict__ flags,  // [256] x 32 u32 (128B-padded)
    int t0, int Tc) {
  __shared__ u16 Wl[64 * 1024];    // 128 KiB: 64 gate-col rows x 1024 k (swizzled)
  __shared__ float zl[4][16][17];  // [gate][batch][hcol]
  const int tid = threadIdx.x;
  const int wgid = blockIdx.x;
  const int g = wgid >> 6, gi = wgid & 63;
  const int bg = g * 16, hc0 = gi * 16;
  const int w = tid >> 6, l = tid & 63;
  const int lc = l & 15, lg = l >> 4;
  const int mb = tid >> 4, j = tid & 15;

  // ---- stage Wh slice -> LDS (swizzled), once ----
  for (int rb = 0; rb < 4; ++rb) {
    const int r = rb * 16 + (tid & 15);       // LDS row
    const int chunk = tid >> 4;               // 64-elem column chunk
    const int q = r >> 4, jj = r & 15;
    const u16* src = whT + ((size_t)(q * 1024 + hc0 + jj)) * 1024 + chunk * 64;
#pragma unroll
    for (int v = 0; v < 8; ++v) {
      bf16x8 d = *(const bf16x8*)(src + v * 8);
      *(bf16x8*)((char*)Wl + swz((unsigned)(r * 2048 + chunk * 128 + v * 16))) = d;
    }
  }
  __syncthreads();

  // ---- hoist B-fragments to registers (static indices only) ----
  const unsigned bbase = (unsigned)((w * 16 + lc) * 2048 + lg * 16);
  bf16x8 bw[32];
#pragma unroll
  for (int kb = 0; kb < 32; ++kb)
    bw[kb] = *(const bf16x8*)((char*)Wl + swz(bbase + kb * 64));

  float creg = cws[(size_t)(bg + mb) * 1024 + hc0 + j];
  unsigned* myflag = flags + (size_t)wgid * 32;
  unsigned* gflag = flags + (size_t)(g * 64 + (tid & 63)) * 32;

  // software-pipelined xz loads
  const float* xbase = xz + (size_t)(bg + mb) * Tc * 4096 + hc0 + j;
  float x0 = xbase[0], x1 = xbase[1024], x2 = xbase[2048], x3 = xbase[3072];

  for (int tt = 0; tt < Tc; ++tt) {
    const int t = t0 + tt;

    // A-frags: LLC-direct (sc1) u64 atomic loads; rows = group's 16 batches
    const u64* hq = (const u64*)(hbuf + (size_t)(t & 1) * 65536 +
                                 (size_t)(bg + lc) * 1024 + lg * 8);
    f32x4 ac0 = {0.f, 0.f, 0.f, 0.f}, ac1 = {0.f, 0.f, 0.f, 0.f};
#pragma unroll
    for (int kb = 0; kb < 32; kb += 2) {
      union { bf16x8 v; u64 q[2]; } a0, a1;
      a0.q[0] = ALOAD64(hq + kb * 8);
      a0.q[1] = ALOAD64(hq + kb * 8 + 1);
      a1.q[0] = ALOAD64(hq + kb * 8 + 8);
      a1.q[1] = ALOAD64(hq + kb * 8 + 9);
      ac0 = MFMA_BF16(a0.v, bw[kb], ac0);
      ac1 = MFMA_BF16(a1.v, bw[kb + 1], ac1);
    }
#pragma unroll
    for (int r = 0; r < 4; ++r) zl[w][lg * 4 + r][lc] = ac0[r] + ac1[r];
    __syncthreads();

    // gate phase: thread (mb, j) owns (batch bg+mb, h-col hc0+j)
    const float zi = zl[0][mb][j] + x0;
    const float zf = zl[1][mb][j] + x1;
    const float zg = zl[2][mb][j] + x2;
    const float zo = zl[3][mb][j] + x3;
    const float cn = sigf(zf) * creg + sigf(zi) * tanh_(zg);
    const float hn = sigf(zo) * tanh_(cn);
    creg = cn;
    out[((size_t)(bg + mb) * 256 + t) * 1024 + hc0 + j] = hn;

    // h store: pack 2 bf16 -> u32, relaxed agent (sc1 -> LLC)
    unsigned hw = (unsigned)f2bf(hn);
    unsigned nb = (unsigned)__shfl_down((int)hw, 1);
    if (!(tid & 1)) {
      unsigned* hp32 = (unsigned*)(hbuf + (size_t)((t + 1) & 1) * 65536 +
                                   (size_t)(bg + mb) * 1024 + hc0 + j);
      ASTORE32(hp32, hw | (nb << 16));
    }

    // prefetch next step's xz before the barrier spin
    if (tt + 1 < Tc) {
      const float* xp = xbase + (size_t)(tt + 1) * 4096;
      x0 = xp[0]; x1 = xp[1024]; x2 = xp[2048]; x3 = xp[3072];
    }

    // ---- per-group flag barrier (no fences; sc1 traffic is LLC-coherent).
    // __syncthreads drains each wave's vmcnt, so all h stores are LLC-acked
    // before tid 0 publishes the flag. ----
    __syncthreads();
    if (tid < 64) {
      if (tid == 0) ASTORE32(myflag, (unsigned)(t + 1));
      unsigned v;
      do {
        v = ALOAD32(gflag);
      } while (v < (unsigned)(t + 1));
    }
    __syncthreads();
  }
  cws[(size_t)(bg + mb) * 1024 + hc0 + j] = creg;
}

extern "C" void kernel_launch(void* const* d_in, const int* in_sizes, int n_in,
                              void* d_out, int out_size, void* d_ws, size_t ws_size,
                              hipStream_t stream) {
  const float* x    = (const float*)d_in[0];
  const float* h0   = (const float*)d_in[1];
  const float* c0   = (const float*)d_in[2];
  const float* Wi   = (const float*)d_in[3];
  const float* Wh   = (const float*)d_in[4];
  const float* bias = (const float*)d_in[5];
  float* out = (float*)d_out;

  char* ws = (char*)d_ws;
  u16*      xb    = (u16*)(ws);                   // 33,554,432 B : x in bf16
  u16*      wiT   = (u16*)(ws + 33554432);        //  8,388,608 B : Wi^T bf16
  u16*      whT   = (u16*)(ws + 41943040);        //  8,388,608 B : Wh^T bf16
  u16*      hbuf  = (u16*)(ws + 50331648);        //    262,144 B : h double-buffer bf16
  float*    cws   = (float*)(ws + 50593792);      //    262,144 B : c state fp32
  unsigned* flags = (unsigned*)(ws + 50855936);   //     32,768 B : barrier flags (128B-padded)
  float*    xz    = (float*)(ws + 50888704);      // Tc*1,048,576 B : xz chunk fp32

  int lgTc = 0;
  for (int lg = 8; lg >= 1; --lg) {
    if (50888704ull + (1ull << lg) * 1048576ull <= ws_size) { lgTc = lg; break; }
  }
  if (lgTc == 0) return;  // workspace too small — fail visibly
  const int Tc = 1 << lgTc;

  k_cvt_x<<<2048, 256, 0, stream>>>(x, xb, (64 * 256 * 1024) / 4);
  dim3 tg(4096 / 64, 1024 / 64);
  k_transpose_cvt<<<tg, 256, 0, stream>>>(Wi, wiT, 1024, 4096);
  k_transpose_cvt<<<tg, 256, 0, stream>>>(Wh, whT, 1024, 4096);
  k_init<<<256, 256, 0, stream>>>(h0, c0, hbuf, cws, flags);

  for (int t0 = 0; t0 < 256; t0 += Tc) {
    k_gemm_xz<<<dim3((64 * Tc / 128) * 32), 256, 0, stream>>>(xb, wiT, bias, xz, t0, lgTc);
    const u16* whT_ = whT;
    const float* xz_ = xz;
    u16* hbuf_ = hbuf;
    float* cws_ = cws;
    float* out_ = out;
    unsigned* flags_ = flags;
    int t0_ = t0, Tc_ = Tc;
    void* args[8] = {(void*)&whT_, (void*)&xz_, (void*)&hbuf_, (void*)&cws_,
                     (void*)&out_, (void*)&flags_, (void*)&t0_, (void*)&Tc_};
    hipLaunchCooperativeKernel((void*)k_recur, dim3(256), dim3(256), args, 0, stream);
  }
}

// Round 4
// 1260.733 us; speedup vs baseline: 7.3780x; 2.2265x over previous
//
#include <hip/hip_runtime.h>

typedef unsigned short u16;
typedef unsigned long long u64;
typedef __attribute__((ext_vector_type(8))) short bf16x8;
typedef __attribute__((ext_vector_type(4))) float f32x4;

#define MFMA_BF16(a, b, c) __builtin_amdgcn_mfma_f32_16x16x32_bf16((a), (b), (c), 0, 0, 0)

#define GLD16(gp, lp)                                                        \
  __builtin_amdgcn_global_load_lds(                                          \
      (const __attribute__((address_space(1))) void*)(gp),                   \
      (__attribute__((address_space(3))) void*)(lp), 16, 0, 0)

#define ALOAD64(p)  __hip_atomic_load((p), __ATOMIC_RELAXED, __HIP_MEMORY_SCOPE_AGENT)
#define ALOAD32(p)  __hip_atomic_load((p), __ATOMIC_RELAXED, __HIP_MEMORY_SCOPE_AGENT)
#define ASTORE64(p, v) __hip_atomic_store((p), (v), __ATOMIC_RELAXED, __HIP_MEMORY_SCOPE_AGENT)

__device__ __forceinline__ u16 f2bf(float f) {
  union { float f; unsigned u; } v;
  v.f = f;
  unsigned r = v.u + 0x7FFFu + ((v.u >> 16) & 1u);
  return (u16)(r >> 16);
}
__device__ __forceinline__ float sigf(float x) { return 1.0f / (1.0f + __expf(-x)); }
__device__ __forceinline__ float tanh_(float x) { return 1.0f - 2.0f / (__expf(2.0f * x) + 1.0f); }
__device__ __forceinline__ unsigned swz(unsigned b) {
  return b ^ ((((b >> 11) ^ (b >> 7)) & 7u) << 4);
}

// ---- x (fp32) -> bf16, vectorized ----
__global__ void k_cvt_x(const float* __restrict__ src, u16* __restrict__ dst, int n4) {
  int i = blockIdx.x * blockDim.x + threadIdx.x;
  int st = gridDim.x * blockDim.x;
  for (; i < n4; i += st) {
    float4 v = reinterpret_cast<const float4*>(src)[i];
    ushort4 o;
    o.x = f2bf(v.x); o.y = f2bf(v.y); o.z = f2bf(v.z); o.w = f2bf(v.w);
    reinterpret_cast<ushort4*>(dst)[i] = o;
  }
}

// ---- transpose (R x C fp32) -> (C x R bf16), 64x64 LDS tiles ----
__global__ void k_transpose_cvt(const float* __restrict__ src, u16* __restrict__ dst,
                                int R, int C) {
  __shared__ float tile[64][65];
  int c0 = blockIdx.x * 64, r0 = blockIdx.y * 64;
  int tx = threadIdx.x & 63, ty = threadIdx.x >> 6;
#pragma unroll
  for (int q = 0; q < 16; ++q) {
    int r = ty + q * 4;
    tile[r][tx] = src[(size_t)(r0 + r) * C + c0 + tx];
  }
  __syncthreads();
#pragma unroll
  for (int q = 0; q < 16; ++q) {
    int r = ty + q * 4;
    dst[(size_t)(c0 + r) * R + r0 + tx] = f2bf(tile[tx][r]);
  }
}

// ---- initial state: h0 -> hbuf[0] (bf16), c0 -> cws (fp32), zero barrier flags ----
__global__ void k_init(const float* __restrict__ h0, const float* __restrict__ c0,
                       u16* __restrict__ hbuf, float* __restrict__ cws,
                       unsigned* __restrict__ flags) {
  int i = blockIdx.x * 256 + threadIdx.x;  // 65536 total
  hbuf[i] = f2bf(h0[i]);
  cws[i] = c0[i];
  if (i < 8192) flags[i] = 0u;
}

// ---- xz = x@Wi + b for a time-chunk; 128x128 tile, BK=32, global_load_lds ----
__global__ __launch_bounds__(256) void k_gemm_xz(
    const u16* __restrict__ xb,   // [64][256][1024] bf16
    const u16* __restrict__ wiT,  // [4096][1024] bf16 (Wi transposed)
    const float* __restrict__ bias,
    float* __restrict__ xz,       // [64*Tc][4096] fp32
    int t0, int lgTc) {
  __shared__ u16 Al[128 * 32];
  __shared__ u16 Bl[128 * 32];
  const int tid = threadIdx.x;
  const int w = tid >> 6, l = tid & 63;
  const int lc = l & 15, lg = l >> 4;
  const int ntm = 1 << (lgTc - 1);            // (64*Tc)/128
  const int tm = blockIdx.x & (ntm - 1);
  const int tn = blockIdx.x >> (lgTc - 1);
  const int m0 = tm << 7, n0 = tn << 7;
  const int mask = (1 << lgTc) - 1;

  const int rowl = w * 32 + (l >> 2);
  const int koff = (l & 3) * 8;
  const int mA0 = m0 + rowl, mA1 = mA0 + 16;
  const size_t xr0 = ((size_t)(mA0 >> lgTc) * 256 + t0 + (mA0 & mask)) * 1024 + koff;
  const size_t xr1 = ((size_t)(mA1 >> lgTc) * 256 + t0 + (mA1 & mask)) * 1024 + koff;
  const size_t br0 = (size_t)(n0 + rowl) * 1024 + koff;
  const size_t br1 = br0 + 16 * 1024;

  u16* a_dst0 = &Al[w * 1024];
  u16* a_dst1 = &Al[w * 1024 + 512];
  u16* b_dst0 = &Bl[w * 1024];
  u16* b_dst1 = &Bl[w * 1024 + 512];

  f32x4 acc[4][4] = {};

  for (int k0 = 0; k0 < 1024; k0 += 32) {
    GLD16(xb + xr0 + k0, a_dst0);
    GLD16(xb + xr1 + k0, a_dst1);
    GLD16(wiT + br0 + k0, b_dst0);
    GLD16(wiT + br1 + k0, b_dst1);
    __syncthreads();
    bf16x8 af[4], bfr[4];
#pragma unroll
    for (int mi = 0; mi < 4; ++mi)
      af[mi] = *(const bf16x8*)&Al[((w & 1) * 64 + mi * 16 + lc) * 32 + lg * 8];
#pragma unroll
    for (int ni = 0; ni < 4; ++ni)
      bfr[ni] = *(const bf16x8*)&Bl[((w >> 1) * 64 + ni * 16 + lc) * 32 + lg * 8];
#pragma unroll
    for (int mi = 0; mi < 4; ++mi)
#pragma unroll
      for (int ni = 0; ni < 4; ++ni)
        acc[mi][ni] = MFMA_BF16(af[mi], bfr[ni], acc[mi][ni]);
    __syncthreads();
  }

  const int mbase = m0 + (w & 1) * 64 + lg * 4;
  const int nbase = n0 + (w >> 1) * 64 + lc;
#pragma unroll
  for (int ni = 0; ni < 4; ++ni) {
    const int n = nbase + ni * 16;
    const float bv = bias[n];
#pragma unroll
    for (int mi = 0; mi < 4; ++mi) {
#pragma unroll
      for (int r = 0; r < 4; ++r) {
        const int m = mbase + mi * 16 + r;
        xz[(size_t)m * 4096 + n] = acc[mi][ni][r] + bv;
      }
    }
  }
}

// ---- recurrence: 4 independent groups x 64 wgs; group g owns batches
//      [16g,16g+16); wg owns 16 h-cols x 4 gates. k-SPLIT: wave w covers
//      k in [256w,256w+256) for ALL 4 gates (partial z reduced in LDS) so
//      each wave loads a distinct quarter of h (4x less LLC traffic).
//      Sync = single-line monotonic counter per group (arrive: 1 atomicAdd
//      per wg; poll: 1 lane per wg). No fences anywhere. ----
__global__ void __launch_bounds__(256, 1) k_recur(
    const u16* __restrict__ whT,   // [4096][1024] bf16 (Wh transposed)
    const float* __restrict__ xz,  // [64*Tc][4096] fp32
    u16* __restrict__ hbuf,        // [2][64*1024] bf16
    float* __restrict__ cws,       // [64*1024] fp32
    float* __restrict__ out,       // [64][256][1024] fp32
    unsigned* __restrict__ flags,  // counters, 128B-padded per group
    int t0, int Tc, int eb) {      // eb = epoch base = chunk_idx*(Tc-1)
  __shared__ u16 Wl[64 * 1024];      // 128 KiB swizzled Wh slice
  __shared__ float zl[4][4][16][17]; // [wave][gate][batch][hcol]
  const int tid = threadIdx.x;
  const int wgid = blockIdx.x;
  const int g = wgid >> 6, gi = wgid & 63;
  const int bg = g * 16, hc0 = gi * 16;
  const int w = tid >> 6, l = tid & 63;
  const int lc = l & 15, lg = l >> 4;
  const int mb = tid >> 4, j = tid & 15;

  // ---- stage Wh slice -> LDS (swizzled), once ----
  for (int rb = 0; rb < 4; ++rb) {
    const int r = rb * 16 + (tid & 15);       // LDS row = gate*16 + col
    const int chunk = tid >> 4;               // 64-elem column chunk
    const int q = r >> 4, jj = r & 15;
    const u16* src = whT + ((size_t)(q * 1024 + hc0 + jj)) * 1024 + chunk * 64;
#pragma unroll
    for (int v = 0; v < 8; ++v) {
      bf16x8 d = *(const bf16x8*)(src + v * 8);
      *(bf16x8*)((char*)Wl + swz((unsigned)(r * 2048 + chunk * 128 + v * 16))) = d;
    }
  }
  __syncthreads();

  // ---- hoist B-fragments: wave w, gate q, k-block kbl in [0,8) ----
  bf16x8 bw[32];  // bw[q*8+kbl]
#pragma unroll
  for (int q = 0; q < 4; ++q)
#pragma unroll
    for (int kbl = 0; kbl < 8; ++kbl)
      bw[q * 8 + kbl] = *(const bf16x8*)((char*)Wl +
          swz((unsigned)((q * 16 + lc) * 2048 + w * 512 + kbl * 64 + lg * 16)));

  float creg = cws[(size_t)(bg + mb) * 1024 + hc0 + j];
  unsigned* cnt = flags + (size_t)g * 32;

  // software-pipelined xz loads
  const float* xbase = xz + (size_t)(bg + mb) * Tc * 4096 + hc0 + j;
  float x0 = xbase[0], x1 = xbase[1024], x2 = xbase[2048], x3 = xbase[3072];

  for (int tt = 0; tt < Tc; ++tt) {
    const int t = t0 + tt;

    // ---- MFMA phase: wave w covers k in [256w, 256w+256) ----
    const u64* hq = (const u64*)(hbuf + (size_t)(t & 1) * 65536 +
                                 (size_t)(bg + lc) * 1024 + w * 256 + lg * 8);
    union { bf16x8 v; u64 q2[2]; } aa[8];
#pragma unroll
    for (int kbl = 0; kbl < 8; ++kbl) {
      aa[kbl].q2[0] = ALOAD64(hq + kbl * 8);
      aa[kbl].q2[1] = ALOAD64(hq + kbl * 8 + 1);
    }
    f32x4 ac[4] = {};
#pragma unroll
    for (int kbl = 0; kbl < 8; ++kbl)
#pragma unroll
      for (int q = 0; q < 4; ++q)
        ac[q] = MFMA_BF16(aa[kbl].v, bw[q * 8 + kbl], ac[q]);
#pragma unroll
    for (int q = 0; q < 4; ++q)
#pragma unroll
      for (int r = 0; r < 4; ++r)
        zl[w][q][lg * 4 + r][lc] = ac[q][r];
    __syncthreads();

    // ---- gate phase: thread (mb, j) owns (batch bg+mb, h-col hc0+j) ----
    const float zi = x0 + zl[0][0][mb][j] + zl[1][0][mb][j] + zl[2][0][mb][j] + zl[3][0][mb][j];
    const float zf = x1 + zl[0][1][mb][j] + zl[1][1][mb][j] + zl[2][1][mb][j] + zl[3][1][mb][j];
    const float zg = x2 + zl[0][2][mb][j] + zl[1][2][mb][j] + zl[2][2][mb][j] + zl[3][2][mb][j];
    const float zo = x3 + zl[0][3][mb][j] + zl[1][3][mb][j] + zl[2][3][mb][j] + zl[3][3][mb][j];
    const float cn = sigf(zf) * creg + sigf(zi) * tanh_(zg);
    const float hn = sigf(zo) * tanh_(cn);
    creg = cn;

    // h store: pack 4 bf16 -> u64, one relaxed agent store per 4 threads
    unsigned hw = (unsigned)f2bf(hn);
    unsigned p01 = hw | ((unsigned)__shfl_down((int)hw, 1) << 16);
    unsigned p23 = (unsigned)__shfl_down((int)p01, 2);
    if ((tid & 3) == 0) {
      u64* hp = (u64*)(hbuf + (size_t)((t + 1) & 1) * 65536 +
                       (size_t)(bg + mb) * 1024 + hc0 + j);
      ASTORE64(hp, (u64)p01 | ((u64)p23 << 32));
    }

    if (tt + 1 < Tc) {
      // ---- barrier: drain h stores, arrive, overlap out+xz, poll ----
      __syncthreads();
      if (tid == 0)
        __hip_atomic_fetch_add(cnt, 1u, __ATOMIC_RELAXED, __HIP_MEMORY_SCOPE_AGENT);
      out[((size_t)(bg + mb) * 256 + t) * 1024 + hc0 + j] = hn;
      const float* xp = xbase + (size_t)(tt + 1) * 4096;
      x0 = xp[0]; x1 = xp[1024]; x2 = xp[2048]; x3 = xp[3072];
      if (tid == 0) {
        const unsigned tgt = 64u * (unsigned)(eb + tt + 1);
        unsigned v;
        do { v = ALOAD32(cnt); } while (v < tgt);
      }
      __syncthreads();
    } else {
      out[((size_t)(bg + mb) * 256 + t) * 1024 + hc0 + j] = hn;
    }
  }
  cws[(size_t)(bg + mb) * 1024 + hc0 + j] = creg;
}

extern "C" void kernel_launch(void* const* d_in, const int* in_sizes, int n_in,
                              void* d_out, int out_size, void* d_ws, size_t ws_size,
                              hipStream_t stream) {
  const float* x    = (const float*)d_in[0];
  const float* h0   = (const float*)d_in[1];
  const float* c0   = (const float*)d_in[2];
  const float* Wi   = (const float*)d_in[3];
  const float* Wh   = (const float*)d_in[4];
  const float* bias = (const float*)d_in[5];
  float* out = (float*)d_out;

  char* ws = (char*)d_ws;
  u16*      xb    = (u16*)(ws);                   // 33,554,432 B : x in bf16
  u16*      wiT   = (u16*)(ws + 33554432);        //  8,388,608 B : Wi^T bf16
  u16*      whT   = (u16*)(ws + 41943040);        //  8,388,608 B : Wh^T bf16
  u16*      hbuf  = (u16*)(ws + 50331648);        //    262,144 B : h double-buffer bf16
  float*    cws   = (float*)(ws + 50593792);      //    262,144 B : c state fp32
  unsigned* flags = (unsigned*)(ws + 50855936);   //     32,768 B : barrier counters
  float*    xz    = (float*)(ws + 50888704);      // Tc*1,048,576 B : xz chunk fp32

  int lgTc = 0;
  for (int lg = 8; lg >= 1; --lg) {
    if (50888704ull + (1ull << lg) * 1048576ull <= ws_size) { lgTc = lg; break; }
  }
  if (lgTc == 0) return;  // workspace too small — fail visibly
  const int Tc = 1 << lgTc;

  k_cvt_x<<<2048, 256, 0, stream>>>(x, xb, (64 * 256 * 1024) / 4);
  dim3 tg(4096 / 64, 1024 / 64);
  k_transpose_cvt<<<tg, 256, 0, stream>>>(Wi, wiT, 1024, 4096);
  k_transpose_cvt<<<tg, 256, 0, stream>>>(Wh, whT, 1024, 4096);
  k_init<<<256, 256, 0, stream>>>(h0, c0, hbuf, cws, flags);

  int chunk = 0;
  for (int t0 = 0; t0 < 256; t0 += Tc, ++chunk) {
    k_gemm_xz<<<dim3((64 * Tc / 128) * 32), 256, 0, stream>>>(xb, wiT, bias, xz, t0, lgTc);
    const u16* whT_ = whT;
    const float* xz_ = xz;
    u16* hbuf_ = hbuf;
    float* cws_ = cws;
    float* out_ = out;
    unsigned* flags_ = flags;
    int t0_ = t0, Tc_ = Tc, eb_ = chunk * (Tc - 1);
    void* args[9] = {(void*)&whT_, (void*)&xz_, (void*)&hbuf_, (void*)&cws_,
                     (void*)&out_, (void*)&flags_, (void*)&t0_, (void*)&Tc_, (void*)&eb_};
    hipLaunchCooperativeKernel((void*)k_recur, dim3(256), dim3(256), args, 0, stream);
  }
}